// Round 8
// baseline (178.188 us; speedup 1.0000x reference)
//
#include <hip/hip_runtime.h>
#include <hip/hip_fp16.h>
#include <math.h>

#define T_DIM 2048
#define B_DIM 2
#define C_DIM 1024
#define H_DIM 16
#define M_DIM 4096   // B*T

typedef _Float16 f16x8 __attribute__((ext_vector_type(8)));
typedef _Float16 f16x4 __attribute__((ext_vector_type(4)));
typedef _Float16 f16x2 __attribute__((ext_vector_type(2)));
typedef float    f32x4 __attribute__((ext_vector_type(4)));

union f16x8_u { f16x8 v; f16x2 h[4]; _Float16 e[8]; };

#if defined(__has_builtin)
#  if __has_builtin(__builtin_amdgcn_fdot2)
#    define HAVE_FDOT2 1
#  endif
#endif

static __device__ __forceinline__ float FDOT2(f16x2 a, f16x2 b, float c)
{
#ifdef HAVE_FDOT2
    return __builtin_amdgcn_fdot2(a, b, c, false);
#else
    return c + (float)a[0] * (float)b[0] + (float)a[1] * (float)b[1];
#endif
}

// async global->LDS, 16 bytes per lane (wave-uniform base + lane*16 dest)
#define ASYNC_COPY16(gsrc, ldst) \
  __builtin_amdgcn_global_load_lds( \
    (__attribute__((address_space(1))) unsigned int*)(gsrc), \
    (__attribute__((address_space(3))) unsigned int*)(ldst), 16, 0, 0)

// ======================================================================
// Fragment-pack layout (for the no-LDS GEMM1):
//   pack[(g*(K/32) + t)*512 + l*8 .. +7]  (f16 units)
//   g = 16-row(A)/16-col(B) group, t = K-step (32 f16), lane l:
//   row/col = g*16 + (l&15), k = t*32 + (l>>4)*8 + j, j=0..7
//   -> one (g,t) chunk = 1024 B = 64 lanes x 16 B, the exact MFMA fragment.
// ======================================================================

// ---------------- prep A: x (fp32 row-major) -> fragment-pack f16 ----------------
// one block per 16-row group g (256 blocks)
__global__ __launch_bounds__(256) void prep_xpack_kernel(const float* __restrict__ x,
                                                         _Float16* __restrict__ xpack)
{
    __shared__ __attribute__((aligned(16))) _Float16 rows[16 * 1032];  // pad: free 2-way banks
    const int g = blockIdx.x;
    const int tid = threadIdx.x;
    // load 16 rows x 1024 f32, convert to f16 in LDS
    const int row = tid >> 4, c16 = tid & 15;
#pragma unroll
    for (int it = 0; it < 16; ++it) {
        const int c4 = (c16 + it * 16) << 2;   // f32 col
        float4 v = *(const float4*)&x[(long)(g * 16 + row) * 1024 + c4];
        f16x4 o;
        o[0] = (_Float16)v.x; o[1] = (_Float16)v.y;
        o[2] = (_Float16)v.z; o[3] = (_Float16)v.w;
        *(f16x4*)&rows[row * 1032 + c4] = o;
    }
    __syncthreads();
    // emit 8 chunks per thread
    const int l = tid & 63, ksb = tid >> 6;
#pragma unroll
    for (int cc = 0; cc < 8; ++cc) {
        const int ks = ksb + cc * 4;           // 0..31
        f16x8 c = *(const f16x8*)&rows[(l & 15) * 1032 + ks * 32 + ((l >> 4) << 3)];
        *(f16x8*)&xpack[((long)(g * 32 + ks)) * 512 + l * 8] = c;
    }
}

// ---------------- prep B: W_attn (K x N fp32) -> fragment-pack f16 ----------------
// one block per 32x32 tile: bk = b%32 (k-step), bn = b/32
__global__ __launch_bounds__(256) void prep_wapack_kernel(const float* __restrict__ W,
                                                          _Float16* __restrict__ wpack)
{
    __shared__ float tile[32][33];
    const int b = blockIdx.x;
    const int bk = b & 31;          // K/32 = 32 k-steps
    const int bn = b >> 5;          // 96 n-tiles
    const int tid = threadIdx.x;
    const int tx = tid & 31, ty = tid >> 5;
    const int N = 3072;
#pragma unroll
    for (int r = ty; r < 32; r += 8)
        tile[r][tx] = W[(long)(bk * 32 + r) * N + bn * 32 + tx];
    __syncthreads();
    if (tid < 128) {
        const int hh = tid >> 6, l = tid & 63;
        const int kb = (l >> 4) << 3;
        f16x8_u o;
#pragma unroll
        for (int j = 0; j < 8; ++j)
            o.e[j] = (_Float16)tile[kb + j][hh * 16 + (l & 15)];
        *(f16x8*)&wpack[((long)((bn * 2 + hh) * 32 + bk)) * 512 + l * 8] = o.v;
    }
}

// ---------------- prep: W_proj transpose -> WpT (N x K f16 row-major, for gemm2) ----------------
__global__ __launch_bounds__(256) void prep_wpt_kernel(const float* __restrict__ W,
                                                       _Float16* __restrict__ WT)
{
    __shared__ float tile[32][33];
    const int N = 1024, K = 1024;
    const int bk = blockIdx.x & 31;
    const int bn = blockIdx.x >> 5;
    const int tx = threadIdx.x & 31, ty = threadIdx.x >> 5;
#pragma unroll
    for (int r = ty; r < 32; r += 8)
        tile[r][tx] = W[(long)(bk * 32 + r) * N + bn * 32 + tx];
    __syncthreads();
#pragma unroll
    for (int r = ty; r < 32; r += 8)
        WT[(long)(bn * 32 + r) * K + bk * 32 + tx] = (_Float16)tile[tx][r];
}

// ---------------- GEMM1: no-LDS streaming MFMA from fragment packs ----------------
// M=4096, N=3072, K=1024. 768 blocks x 4 waves; wave tile 64x64.
// mw = bid%64 (A row-block), nw = (bid/64)*4 + wid (B col-block).
// Zero LDS, zero barriers: waves stream coalesced 1KB fragment chunks from L1/L2.
__global__ __launch_bounds__(256) void gemm1_stream_kernel(const _Float16* __restrict__ Apack,
                                                           const _Float16* __restrict__ Bpack,
                                                           _Float16* __restrict__ C)
{
    const int lane = threadIdx.x & 63;
    const int wid  = threadIdx.x >> 6;
    // XCD-aware bijective swizzle (768 % 8 == 0)
    const int bid = ((int)blockIdx.x & 7) * 96 + ((int)blockIdx.x >> 3);
    const int mw = bid & 63;
    const int nw = (bid >> 6) * 4 + wid;

    const _Float16* abase = Apack + ((long)(mw * 4) * 32) * 512 + lane * 8;
    const _Float16* bbase = Bpack + ((long)(nw * 4) * 32) * 512 + lane * 8;

    f32x4 acc[4][4] = {};

#pragma unroll 2
    for (int t = 0; t < 32; ++t) {
        f16x8 af[4], bf[4];
#pragma unroll
        for (int i = 0; i < 4; i++) af[i] = *(const f16x8*)(abase + (i * 32 + t) * 512);
#pragma unroll
        for (int j = 0; j < 4; j++) bf[j] = *(const f16x8*)(bbase + (j * 32 + t) * 512);
#pragma unroll
        for (int i = 0; i < 4; i++)
#pragma unroll
            for (int j = 0; j < 4; j++)
                acc[i][j] = __builtin_amdgcn_mfma_f32_16x16x32_f16(af[i], bf[j], acc[i][j], 0, 0, 0);
    }

    // epilogue: C/D col = lane&15, row = (lane>>4)*4 + r ; row-major f16 out
    const int fr = lane & 15;
    const int rsub = (lane >> 4) << 2;
#pragma unroll
    for (int j = 0; j < 4; j++) {
        const int col = nw * 64 + j * 16 + fr;
#pragma unroll
        for (int i = 0; i < 4; i++) {
            const int rbase = mw * 64 + i * 16 + rsub;
#pragma unroll
            for (int r = 0; r < 4; r++)
                C[(long)(rbase + r) * 3072 + col] = (_Float16)acc[i][j][r];
        }
    }
}

// ---------------- GEMM2 (ring-3 LDS, counted vmcnt): out = LN(tanh(yh @ WpT^T)) ----------------
template<int BM>
__global__ __launch_bounds__(256) void gemm2_kernel(
    const _Float16* __restrict__ A, const _Float16* __restrict__ Bt,
    float* __restrict__ Cv, int M, int N, int K,
    const float* __restrict__ ln_scale, const float* __restrict__ ln_delta,
    const float* __restrict__ ln_bias)
{
    constexpr int M_REP   = BM / 32;
    constexpr int A_LOADS = BM / 64;
    constexpr int LPT     = A_LOADS + 2;
    __shared__ __attribute__((aligned(16))) _Float16 As[3][BM * 32];
    __shared__ __attribute__((aligned(16))) _Float16 Bs[3][128 * 32];

    const int tid  = threadIdx.x;
    const int lane = tid & 63;
    const int wave = tid >> 6;
    const int wr = wave >> 1, wc = wave & 1;

    const int nwg = gridDim.x;
    const int q8  = nwg >> 3;
    const int bid = ((int)blockIdx.x & 7) * q8 + ((int)blockIdx.x >> 3);

    const int ntn = N >> 7;
    const int m0 = (bid / ntn) * BM;
    const int n0 = (bid % ntn) << 7;

    f32x4 acc[M_REP][4] = {};

    const int ea   = tid * 8;
    const int erow = ea >> 5;
    const int xm   = ((erow & 2) << 3) | ((erow & 4) << 1);
    const int ecs  = (ea & 31) ^ xm;
    const _Float16* aptr[A_LOADS];
    const _Float16* bptr[2];
#pragma unroll
    for (int l = 0; l < A_LOADS; ++l)
        aptr[l] = A + (long)(m0 + erow + l * 64) * K + ecs;
#pragma unroll
    for (int l = 0; l < 2; ++l)
        bptr[l] = Bt + (long)(n0 + erow + l * 64) * K + ecs;

    const int fr = lane & 15;
    const int kb = (lane >> 4) << 3;
    const int xr = ((fr & 2) << 3) | ((fr & 4) << 1);
    const int kbs = kb ^ xr;
    const int NT = K >> 5;

    auto stage = [&](int tile, int slot) {
        const int k0 = tile << 5;
#pragma unroll
        for (int l = 0; l < A_LOADS; ++l) ASYNC_COPY16(aptr[l] + k0, &As[slot][ea + l * 2048]);
#pragma unroll
        for (int l = 0; l < 2; ++l)       ASYNC_COPY16(bptr[l] + k0, &Bs[slot][ea + l * 2048]);
    };

    stage(0, 0);
    stage(1, 1);

    int s = 0;
    for (int t = 0; t < NT; ++t) {
        if (t + 2 < NT) {
            int s2 = s + 2; if (s2 >= 3) s2 -= 3;
            stage(t + 2, s2);
        }
        const int rem = NT - 1 - t;
        if (rem >= 2)      asm volatile("s_waitcnt vmcnt(6)" ::: "memory");
        else if (rem == 1) asm volatile("s_waitcnt vmcnt(3)" ::: "memory");
        else               asm volatile("s_waitcnt vmcnt(0)" ::: "memory");
        __syncthreads();

        f16x8 af[M_REP], bf[4];
#pragma unroll
        for (int i = 0; i < M_REP; i++)
            af[i] = *(const f16x8*)&As[s][((wr * (BM / 2) + (i << 4) + fr) << 5) + kbs];
#pragma unroll
        for (int j = 0; j < 4; j++)
            bf[j] = *(const f16x8*)&Bs[s][(((wc << 6) + (j << 4) + fr) << 5) + kbs];
        __builtin_amdgcn_s_setprio(1);
#pragma unroll
        for (int i = 0; i < M_REP; i++)
#pragma unroll
            for (int j = 0; j < 4; j++)
                acc[i][j] = __builtin_amdgcn_mfma_f32_16x16x32_f16(af[i], bf[j], acc[i][j], 0, 0, 0);
        __builtin_amdgcn_s_setprio(0);
        if (t + 1 < NT) __syncthreads();
        ++s; if (s == 3) s = 0;
    }

    const int rsub = (lane >> 4) << 2;
    const float lsc = ln_scale[0];
#pragma unroll
    for (int j = 0; j < 4; j++) {
        const int col = n0 + (wc << 6) + (j << 4) + fr;
        const float ld = ln_delta[col], lb = ln_bias[col];
#pragma unroll
        for (int i = 0; i < M_REP; i++) {
            const int rbase = m0 + wr * (BM / 2) + (i << 4) + rsub;
#pragma unroll
            for (int r = 0; r < 4; r++) {
                float v = acc[i][j][r];
                v = ld * tanhf(lsc * v) + lb;
                Cv[(long)(rbase + r) * N + col] = v;
            }
        }
    }
}

// ---------------- spiral: two steps on (q,k); v (3rd comp) by value ----------------
__device__ __forceinline__ void spiral2(float& xi, float& xj, float xl)
{
    const float CS = 0.9950041652780258f;   // cos(0.1)
    const float SN = 0.09983341664682815f;  // sin(0.1)
#pragma unroll
    for (int s = 0; s < 2; s++) {
        float r = sqrtf(xi * xi + xj * xj + xl * xl);
        r = fmaxf(r, 1e-8f);
        const float coef = (6.0f - r) / r;
        const float yi = CS * xi - SN * xj;
        const float yj = SN * xi + CS * xj;
        const float nxi = xi + 0.1f * (yi - xi + coef * xi);
        const float nxj = xj + 0.1f * (yj - xj + coef * xj);
        const float nxl = xl + 0.1f * (coef * xl);
        xi = nxi; xj = nxj; xl = nxl;
    }
}

// ---------------- local causal windowed attention, fused spiral, lane-per-row ----------------
#define TB   128
#define ROWS 144
#define LDR  72

__global__ __launch_bounds__(128) void attn_kernel(const _Float16* __restrict__ qkv,
                                                   const float* __restrict__ sinks,
                                                   _Float16* __restrict__ yh)
{
    __shared__ __attribute__((aligned(16))) _Float16 k_lds[ROWS * LDR];
    __shared__ __attribute__((aligned(16))) _Float16 v_lds[ROWS * LDR];
    __shared__ __attribute__((aligned(16))) _Float16 q_lds[TB * LDR];

    const int tid = threadIdx.x;
    const int chunk = blockIdx.x & 15;
    const int h = (blockIdx.x >> 4) & 15;
    const int b = blockIdx.x >> 8;
    const int t0 = chunk * TB;
    const long bT = (long)b * T_DIM;

    for (int s = tid; s < ROWS * 4; s += 128) {
        const int ri = s >> 2, q4 = s & 3;
        const int gr = min(max(t0 - 16 + ri, 0), T_DIM - 1);
        const _Float16* base = qkv + (bT + gr) * 3072 + (h << 6) + (q4 << 4);
        f16x8_u qa, qb, ka, kb2, va, vb;
        qa.v  = *(const f16x8*)(base);        qb.v  = *(const f16x8*)(base + 8);
        ka.v  = *(const f16x8*)(base + 1024); kb2.v = *(const f16x8*)(base + 1032);
        va.v  = *(const f16x8*)(base + 2048); vb.v  = *(const f16x8*)(base + 2056);
        float qq[16], kk[16], vv[16];
#pragma unroll
        for (int u = 0; u < 8; u++) {
            qq[u] = (float)qa.e[u]; qq[8 + u] = (float)qb.e[u];
            kk[u] = (float)ka.e[u]; kk[8 + u] = (float)kb2.e[u];
            vv[u] = (float)va.e[u]; vv[8 + u] = (float)vb.e[u];
        }
#pragma unroll
        for (int u = 0; u < 16; u++) spiral2(qq[u], kk[u], vv[u]);
        const int lbase = ri * LDR + (q4 << 4);
        f16x8_u ko0, ko1, vo0, vo1;
#pragma unroll
        for (int u = 0; u < 8; u++) {
            ko0.e[u] = (_Float16)kk[u]; ko1.e[u] = (_Float16)kk[8 + u];
            vo0.e[u] = (_Float16)vv[u]; vo1.e[u] = (_Float16)vv[8 + u];
        }
        *(f16x8*)&k_lds[lbase]     = ko0.v;
        *(f16x8*)&k_lds[lbase + 8] = ko1.v;
        *(f16x8*)&v_lds[lbase]     = vo0.v;
        *(f16x8*)&v_lds[lbase + 8] = vo1.v;
        if (ri >= 16) {
            const int qbase = (ri - 16) * LDR + (q4 << 4);
            f16x8_u qo0, qo1;
#pragma unroll
            for (int u = 0; u < 8; u++) {
                qo0.e[u] = (_Float16)(qq[u] * 0.125f);
                qo1.e[u] = (_Float16)(qq[8 + u] * 0.125f);
            }
            *(f16x8*)&q_lds[qbase]     = qo0.v;
            *(f16x8*)&q_lds[qbase + 8] = qo1.v;
        }
    }
    __syncthreads();

    f16x8_u qv[8];
#pragma unroll
    for (int u = 0; u < 8; u++) qv[u].v = *(const f16x8*)&q_lds[tid * LDR + u * 8];

    float sc[17];
#pragma unroll
    for (int j = 0; j < 17; j++) {
        const _Float16* kr = &k_lds[(tid + j) * LDR];
        float s = 0.f;
#pragma unroll
        for (int u = 0; u < 8; u++) {
            f16x8_u kx; kx.v = *(const f16x8*)&kr[u * 8];
#pragma unroll
            for (int p = 0; p < 4; p++) s = FDOT2(qv[u].h[p], kx.h[p], s);
        }
        sc[j] = s;
    }

    const int t = t0 + tid;
#pragma unroll
    for (int j = 0; j < 17; j++)
        if (j + t < 16) sc[j] = -INFINITY;
    const float sink = sinks[h];
    float m = sink;
#pragma unroll
    for (int j = 0; j < 17; j++) m = fmaxf(m, sc[j]);
    float e[17];
    float denom = expf(sink - m);
#pragma unroll
    for (int j = 0; j < 17; j++) { e[j] = expf(sc[j] - m); denom += e[j]; }
    const float rden = 1.f / denom;
#pragma unroll
    for (int j = 0; j < 17; j++) e[j] *= rden;

    float yacc[64];
#pragma unroll
    for (int d = 0; d < 64; d++) yacc[d] = 0.f;
#pragma unroll
    for (int j = 0; j < 17; j++) {
        const float a = e[j];
        const _Float16* vr = &v_lds[(tid + j) * LDR];
#pragma unroll
        for (int u = 0; u < 8; u++) {
            f16x8_u vx; vx.v = *(const f16x8*)&vr[u * 8];
#pragma unroll
            for (int z = 0; z < 8; z++) yacc[u * 8 + z] += a * (float)vx.e[z];
        }
    }

#pragma unroll
    for (int u = 0; u < 8; u++) {
        f16x8_u yo;
#pragma unroll
        for (int z = 0; z < 8; z++) yo.e[z] = (_Float16)yacc[u * 8 + z];
        *(f16x8*)&q_lds[tid * LDR + u * 8] = yo.v;
    }
    __syncthreads();
    const int ch = tid & 7, rb = tid >> 3;
#pragma unroll
    for (int pass = 0; pass < 8; ++pass) {
        const int r = pass * 16 + rb;
        *(f16x8*)(yh + (bT + t0 + r) * 1024 + (h << 6) + ch * 8) =
            *(const f16x8*)&q_lds[r * LDR + ch * 8];
    }
}

extern "C" void kernel_launch(void* const* d_in, const int* in_sizes, int n_in,
                              void* d_out, int out_size, void* d_ws, size_t ws_size,
                              hipStream_t stream)
{
    const float* x        = (const float*)d_in[0];
    const float* W_attn   = (const float*)d_in[1];
    const float* W_proj   = (const float*)d_in[2];
    const float* sinks    = (const float*)d_in[3];
    const float* ln_scale = (const float*)d_in[4];
    const float* ln_delta = (const float*)d_in[5];
    const float* ln_bias  = (const float*)d_in[6];
    float* out = (float*)d_out;

    char* ws = (char*)d_ws;
    _Float16* xpack  = (_Float16*)(ws);                          //  8 MiB: A-pack 4096x1024
    _Float16* wapack = (_Float16*)(ws + (size_t)( 8u << 20));    //  6 MiB: B-pack 3072x1024
    _Float16* WpT    = (_Float16*)(ws + (size_t)(14u << 20));    //  2 MiB: 1024x1024 f16
    _Float16* qkv16  = (_Float16*)(ws + (size_t)(16u << 20));    // 24 MiB: 4096x3072 f16
    _Float16* yh     = (_Float16*)(ws + (size_t)(40u << 20));    //  8 MiB: 4096x1024 f16

    // 1. prep: fragment-packs for gemm1, row-major transpose for gemm2
    prep_xpack_kernel <<<256,  256, 0, stream>>>(x, xpack);
    prep_wapack_kernel<<<3072, 256, 0, stream>>>(W_attn, wapack);
    prep_wpt_kernel   <<<1024, 256, 0, stream>>>(W_proj, WpT);
    // 2. qkv = x @ W_attn (f16 out) — no-LDS streaming MFMA
    gemm1_stream_kernel<<<768, 256, 0, stream>>>(xpack, wapack, qkv16);
    // 3. fused spiral^2 + local attention -> yh
    attn_kernel<<<512, 128, 0, stream>>>(qkv16, sinks, yh);
    // 4. out = ln_delta * tanh(ln_scale * (yh @ W_proj)) + ln_bias
    gemm2_kernel<64><<<64 * 8, 256, 0, stream>>>(yh, WpT, out, 4096, 1024, 1024,
                                                 ln_scale, ln_delta, ln_bias);
}

// Round 9
// 176.548 us; speedup vs baseline: 1.0093x; 1.0093x over previous
//
#include <hip/hip_runtime.h>
#include <hip/hip_fp16.h>
#include <math.h>

#define T_DIM 2048
#define B_DIM 2
#define C_DIM 1024
#define H_DIM 16
#define M_DIM 4096   // B*T

typedef _Float16 f16x8 __attribute__((ext_vector_type(8)));
typedef _Float16 f16x4 __attribute__((ext_vector_type(4)));
typedef _Float16 f16x2 __attribute__((ext_vector_type(2)));
typedef float    f32x4 __attribute__((ext_vector_type(4)));

union f16x8_u { f16x8 v; f16x2 h[4]; _Float16 e[8]; };

#if defined(__has_builtin)
#  if __has_builtin(__builtin_amdgcn_fdot2)
#    define HAVE_FDOT2 1
#  endif
#endif

static __device__ __forceinline__ float FDOT2(f16x2 a, f16x2 b, float c)
{
#ifdef HAVE_FDOT2
    return __builtin_amdgcn_fdot2(a, b, c, false);
#else
    return c + (float)a[0] * (float)b[0] + (float)a[1] * (float)b[1];
#endif
}

// async global->LDS, 16 bytes per lane (wave-uniform base + lane*16 dest)
#define ASYNC_COPY16(gsrc, ldst) \
  __builtin_amdgcn_global_load_lds( \
    (__attribute__((address_space(1))) unsigned int*)(gsrc), \
    (__attribute__((address_space(3))) unsigned int*)(ldst), 16, 0, 0)

// ======================================================================
// Fragment-pack layout (A of gemm1, B of gemm2):
//   pack[(g*32 + t)*512 + l*8 .. +7]  (f16 units)
//   g = 16-row/col group, t = K-step (32 f16), lane l:
//   row/col = g*16 + (l&15), k = t*32 + (l>>4)*8 + j
//   -> one (g,t) chunk = 1024 B = the exact per-wave MFMA fragment, coalesced.
// ======================================================================

// ---------------- fused prep: xpack + WaT transpose + Wp pack ----------------
// blocks: [0,256) xpack; [256,3328) WaT; [3328,4352) Wp pack
__global__ __launch_bounds__(256) void prep_kernel(const float* __restrict__ x,
                                                   const float* __restrict__ Wa,
                                                   const float* __restrict__ Wp,
                                                   _Float16* __restrict__ xpack,
                                                   _Float16* __restrict__ WaT,
                                                   _Float16* __restrict__ wppack)
{
    const int bid = blockIdx.x;
    const int tid = threadIdx.x;
    if (bid < 256) {
        // ---- x (fp32 row-major) -> fragment pack ----
        __shared__ __attribute__((aligned(16))) _Float16 rows[16 * 1032];
        const int g = bid;
        const int row = tid >> 4, c16 = tid & 15;
#pragma unroll
        for (int it = 0; it < 16; ++it) {
            const int c4 = (c16 + it * 16) << 2;
            float4 v = *(const float4*)&x[(long)(g * 16 + row) * 1024 + c4];
            f16x4 o;
            o[0] = (_Float16)v.x; o[1] = (_Float16)v.y;
            o[2] = (_Float16)v.z; o[3] = (_Float16)v.w;
            *(f16x4*)&rows[row * 1032 + c4] = o;
        }
        __syncthreads();
        const int l = tid & 63, ksb = tid >> 6;
#pragma unroll
        for (int cc = 0; cc < 8; ++cc) {
            const int ks = ksb + cc * 4;
            f16x8 c = *(const f16x8*)&rows[(l & 15) * 1032 + ks * 32 + ((l >> 4) << 3)];
            *(f16x8*)&xpack[((long)(g * 32 + ks)) * 512 + l * 8] = c;
        }
        return;
    }
    if (bid < 3328) {
        // ---- W_attn (1024 x 3072) -> WaT (3072 x 1024 f16 row-major) ----
        __shared__ float tile[32][33];
        const int b = bid - 256;
        const int bk = b & 31, bn = b >> 5;
        const int tx = tid & 31, ty = tid >> 5;
        const int N = 3072, K = 1024;
#pragma unroll
        for (int r = ty; r < 32; r += 8)
            tile[r][tx] = Wa[(long)(bk * 32 + r) * N + bn * 32 + tx];
        __syncthreads();
#pragma unroll
        for (int r = ty; r < 32; r += 8)
            WaT[(long)(bn * 32 + r) * K + bk * 32 + tx] = (_Float16)tile[tx][r];
        return;
    }
    // ---- W_proj (1024 x 1024) -> fragment pack ----
    {
        __shared__ float tile[32][33];
        const int b = bid - 3328;
        const int bk = b & 31, bn = b >> 5;   // bn 0..31
        const int tx = tid & 31, ty = tid >> 5;
        const int N = 1024;
#pragma unroll
        for (int r = ty; r < 32; r += 8)
            tile[r][tx] = Wp[(long)(bk * 32 + r) * N + bn * 32 + tx];
        __syncthreads();
        if (tid < 128) {
            const int hh = tid >> 6, l = tid & 63;
            const int kb = (l >> 4) << 3;
            f16x8_u o;
#pragma unroll
            for (int j = 0; j < 8; ++j)
                o.e[j] = (_Float16)tile[kb + j][hh * 16 + (l & 15)];
            *(f16x8*)&wppack[((long)((bn * 2 + hh) * 32 + bk)) * 512 + l * 8] = o.v;
        }
    }
}

// ---------------- GEMM1: A streamed from pack (reg-dbuf), B ring-3 LDS ----------------
// M=4096 N=3072 K=1024, 128x128 tile, 4 waves (2x2), wave tile 64x64.
// Raw s_barrier + counted vmcnt (T4): steady vmcnt(8) keeps B(t+1),A(t+1),B(t+2) in flight.
__global__ __launch_bounds__(256) void gemm1_kernel(const _Float16* __restrict__ Apack,
                                                    const _Float16* __restrict__ Bt,
                                                    _Float16* __restrict__ C)
{
    __shared__ __attribute__((aligned(16))) _Float16 Bs[3][128 * 32];   // 24 KB

    const int tid  = threadIdx.x;
    const int lane = tid & 63;
    const int wave = tid >> 6;
    const int wr = wave >> 1, wc = wave & 1;
    const int K = 1024, N = 3072;

    const int bid = ((int)blockIdx.x & 7) * 96 + ((int)blockIdx.x >> 3);  // 768%8==0
    const int m0 = (bid / 24) << 7;
    const int n0 = (bid % 24) << 7;

    f32x4 acc[4][4] = {};

    // B staging (2 loads/thread), r7-verified both-sides swizzle
    const int ea   = tid * 8;
    const int erow = ea >> 5;
    const int xm   = ((erow & 2) << 3) | ((erow & 4) << 1);
    const int ecs  = (ea & 31) ^ xm;
    const _Float16* bptr0 = Bt + (long)(n0 + erow) * K + ecs;
    const _Float16* bptr1 = Bt + (long)(n0 + erow + 64) * K + ecs;

    const int fr = lane & 15;
    const int kb = (lane >> 4) << 3;
    const int xr = ((fr & 2) << 3) | ((fr & 4) << 1);
    const int kbs = kb ^ xr;

    // A stream base: wave's 4 groups g0..g0+3 (rows m0 + wr*64 .. +64)
    const _Float16* abase = Apack + ((long)((m0 >> 4) + wr * 4) * 32) * 512 + lane * 8;

#define G1_STAGE(tile, slot) do { \
        ASYNC_COPY16(bptr0 + ((tile) << 5), &Bs[slot][ea]); \
        ASYNC_COPY16(bptr1 + ((tile) << 5), &Bs[slot][ea + 2048]); } while (0)
#define G1_LOADA(dst, t) do { \
        dst[0] = *(const f16x8*)(abase + ((0 * 32 + (t)) * 512)); \
        dst[1] = *(const f16x8*)(abase + ((1 * 32 + (t)) * 512)); \
        dst[2] = *(const f16x8*)(abase + ((2 * 32 + (t)) * 512)); \
        dst[3] = *(const f16x8*)(abase + ((3 * 32 + (t)) * 512)); } while (0)

    f16x8 afA[4], afB[4];
    G1_STAGE(0, 0);
    G1_STAGE(1, 1);
    G1_LOADA(afA, 0);

#define G1_BODY(t, CUR, NXT, slot, slot2) do { \
        if ((t) + 1 < 32) G1_LOADA(NXT, (t) + 1); \
        if ((t) + 2 < 32) G1_STAGE((t) + 2, slot2); \
        const int rem = 31 - (t); \
        if (rem >= 2)      asm volatile("s_waitcnt vmcnt(8)" ::: "memory"); \
        else if (rem == 1) asm volatile("s_waitcnt vmcnt(6)" ::: "memory"); \
        else               asm volatile("s_waitcnt vmcnt(0)" ::: "memory"); \
        __builtin_amdgcn_s_barrier(); \
        __builtin_amdgcn_sched_barrier(0); \
        f16x8 bf[4]; \
        _Pragma("unroll") \
        for (int j = 0; j < 4; j++) \
            bf[j] = *(const f16x8*)&Bs[slot][(((wc << 6) + (j << 4) + fr) << 5) + kbs]; \
        __builtin_amdgcn_s_setprio(1); \
        _Pragma("unroll") \
        for (int i = 0; i < 4; i++) \
            _Pragma("unroll") \
            for (int j = 0; j < 4; j++) \
                acc[i][j] = __builtin_amdgcn_mfma_f32_16x16x32_f16(CUR[i], bf[j], acc[i][j], 0, 0, 0); \
        __builtin_amdgcn_s_setprio(0); \
        __builtin_amdgcn_s_barrier(); \
        __builtin_amdgcn_sched_barrier(0); } while (0)

    {
        int s = 0;
#pragma unroll 1
        for (int t = 0; t < 32; t += 2) {
            int s1 = s + 1; if (s1 >= 3) s1 -= 3;
            int s2 = s + 2; if (s2 >= 3) s2 -= 3;
            G1_BODY(t,     afA, afB, s,  s2);
            G1_BODY(t + 1, afB, afA, s1, s);   // slot2 for t+3 = (s+3)%3 = s
            s = s2;
        }
    }

    // epilogue: f16 row-major C
    const int rsub = (lane >> 4) << 2;
#pragma unroll
    for (int j = 0; j < 4; j++) {
        const int col = n0 + (wc << 6) + (j << 4) + fr;
#pragma unroll
        for (int i = 0; i < 4; i++) {
            const int rbase = m0 + (wr << 6) + (i << 4) + rsub;
#pragma unroll
            for (int r = 0; r < 4; r++)
                C[(long)(rbase + r) * N + col] = (_Float16)acc[i][j][r];
        }
    }
#undef G1_STAGE
#undef G1_LOADA
#undef G1_BODY
}

// ---------------- GEMM2: A(yh) ring-3 LDS, B streamed from Wp pack ----------------
// M=4096 N=1024 K=1024, 64x128 tile, 4 waves (2x2), wave tile 32x64. LN-tanh epilogue.
__global__ __launch_bounds__(256) void gemm2_kernel(const _Float16* __restrict__ A,
                                                    const _Float16* __restrict__ Bpack,
                                                    float* __restrict__ Cv,
                                                    const float* __restrict__ ln_scale,
                                                    const float* __restrict__ ln_delta,
                                                    const float* __restrict__ ln_bias)
{
    __shared__ __attribute__((aligned(16))) _Float16 As[3][64 * 32];   // 12 KB

    const int tid  = threadIdx.x;
    const int lane = tid & 63;
    const int wave = tid >> 6;
    const int wr = wave >> 1, wc = wave & 1;
    const int K = 1024, N = 1024;

    const int bid = ((int)blockIdx.x & 7) * 64 + ((int)blockIdx.x >> 3);  // 512%8==0
    const int m0 = (bid >> 3) << 6;    // 64 m-tiles
    const int n0 = (bid & 7) << 7;     // 8 n-tiles

    f32x4 acc[2][4] = {};

    // A staging (1 load/thread) with swizzle
    const int ea   = tid * 8;
    const int erow = ea >> 5;          // 0..63
    const int xm   = ((erow & 2) << 3) | ((erow & 4) << 1);
    const int ecs  = (ea & 31) ^ xm;
    const _Float16* aptr = A + (long)(m0 + erow) * K + ecs;

    const int fr = lane & 15;
    const int kb = (lane >> 4) << 3;
    const int xr = ((fr & 2) << 3) | ((fr & 4) << 1);
    const int kbs = kb ^ xr;

    const _Float16* bbase = Bpack + ((long)((n0 >> 4) + wc * 4) * 32) * 512 + lane * 8;

#define G2_STAGE(tile, slot) ASYNC_COPY16(aptr + ((tile) << 5), &As[slot][ea])
#define G2_LOADB(dst, t) do { \
        dst[0] = *(const f16x8*)(bbase + ((0 * 32 + (t)) * 512)); \
        dst[1] = *(const f16x8*)(bbase + ((1 * 32 + (t)) * 512)); \
        dst[2] = *(const f16x8*)(bbase + ((2 * 32 + (t)) * 512)); \
        dst[3] = *(const f16x8*)(bbase + ((3 * 32 + (t)) * 512)); } while (0)

    f16x8 bfA[4], bfB[4];
    G2_STAGE(0, 0);
    G2_STAGE(1, 1);
    G2_LOADB(bfA, 0);

#define G2_BODY(t, CUR, NXT, slot, slot2) do { \
        if ((t) + 1 < 32) G2_LOADB(NXT, (t) + 1); \
        if ((t) + 2 < 32) G2_STAGE((t) + 2, slot2); \
        const int rem = 31 - (t); \
        if (rem >= 2)      asm volatile("s_waitcnt vmcnt(10)" ::: "memory"); \
        else if (rem == 1) asm volatile("s_waitcnt vmcnt(9)" ::: "memory"); \
        else               asm volatile("s_waitcnt vmcnt(0)" ::: "memory"); \
        __builtin_amdgcn_s_barrier(); \
        __builtin_amdgcn_sched_barrier(0); \
        f16x8 af[2]; \
        _Pragma("unroll") \
        for (int i = 0; i < 2; i++) \
            af[i] = *(const f16x8*)&As[slot][(((wr << 5) + (i << 4) + fr) << 5) + kbs]; \
        __builtin_amdgcn_s_setprio(1); \
        _Pragma("unroll") \
        for (int i = 0; i < 2; i++) \
            _Pragma("unroll") \
            for (int j = 0; j < 4; j++) \
                acc[i][j] = __builtin_amdgcn_mfma_f32_16x16x32_f16(af[i], CUR[j], acc[i][j], 0, 0, 0); \
        __builtin_amdgcn_s_setprio(0); \
        __builtin_amdgcn_s_barrier(); \
        __builtin_amdgcn_sched_barrier(0); } while (0)

    {
        int s = 0;
#pragma unroll 1
        for (int t = 0; t < 32; t += 2) {
            int s1 = s + 1; if (s1 >= 3) s1 -= 3;
            int s2 = s + 2; if (s2 >= 3) s2 -= 3;
            G2_BODY(t,     bfA, bfB, s,  s2);
            G2_BODY(t + 1, bfB, bfA, s1, s);
            s = s2;
        }
    }

    const int rsub = (lane >> 4) << 2;
    const float lsc = ln_scale[0];
#pragma unroll
    for (int j = 0; j < 4; j++) {
        const int col = n0 + (wc << 6) + (j << 4) + fr;
        const float ld = ln_delta[col], lb = ln_bias[col];
#pragma unroll
        for (int i = 0; i < 2; i++) {
            const int rbase = m0 + (wr << 5) + (i << 4) + rsub;
#pragma unroll
            for (int r = 0; r < 4; r++) {
                float v = acc[i][j][r];
                Cv[(long)(rbase + r) * N + col] = ld * tanhf(lsc * v) + lb;
            }
        }
    }
#undef G2_STAGE
#undef G2_LOADB
#undef G2_BODY
}

// ---------------- spiral: two steps on (q,k); v (3rd comp) by value ----------------
__device__ __forceinline__ void spiral2(float& xi, float& xj, float xl)
{
    const float CS = 0.9950041652780258f;   // cos(0.1)
    const float SN = 0.09983341664682815f;  // sin(0.1)
#pragma unroll
    for (int s = 0; s < 2; s++) {
        float r = sqrtf(xi * xi + xj * xj + xl * xl);
        r = fmaxf(r, 1e-8f);
        const float coef = (6.0f - r) / r;
        const float yi = CS * xi - SN * xj;
        const float yj = SN * xi + CS * xj;
        const float nxi = xi + 0.1f * (yi - xi + coef * xi);
        const float nxj = xj + 0.1f * (yj - xj + coef * xj);
        const float nxl = xl + 0.1f * (coef * xl);
        xi = nxi; xj = nxj; xl = nxl;
    }
}

// ---------------- local causal windowed attention, fused spiral, lane-per-row ----------------
#define TB   128
#define ROWS 144
#define LDR  72

__global__ __launch_bounds__(128) void attn_kernel(const _Float16* __restrict__ qkv,
                                                   const float* __restrict__ sinks,
                                                   _Float16* __restrict__ yh)
{
    __shared__ __attribute__((aligned(16))) _Float16 k_lds[ROWS * LDR];
    __shared__ __attribute__((aligned(16))) _Float16 v_lds[ROWS * LDR];
    __shared__ __attribute__((aligned(16))) _Float16 q_lds[TB * LDR];

    const int tid = threadIdx.x;
    const int chunk = blockIdx.x & 15;
    const int h = (blockIdx.x >> 4) & 15;
    const int b = blockIdx.x >> 8;
    const int t0 = chunk * TB;
    const long bT = (long)b * T_DIM;

    for (int s = tid; s < ROWS * 4; s += 128) {
        const int ri = s >> 2, q4 = s & 3;
        const int gr = min(max(t0 - 16 + ri, 0), T_DIM - 1);
        const _Float16* base = qkv + (bT + gr) * 3072 + (h << 6) + (q4 << 4);
        f16x8_u qa, qb, ka, kb2, va, vb;
        qa.v  = *(const f16x8*)(base);        qb.v  = *(const f16x8*)(base + 8);
        ka.v  = *(const f16x8*)(base + 1024); kb2.v = *(const f16x8*)(base + 1032);
        va.v  = *(const f16x8*)(base + 2048); vb.v  = *(const f16x8*)(base + 2056);
        float qq[16], kk[16], vv[16];
#pragma unroll
        for (int u = 0; u < 8; u++) {
            qq[u] = (float)qa.e[u]; qq[8 + u] = (float)qb.e[u];
            kk[u] = (float)ka.e[u]; kk[8 + u] = (float)kb2.e[u];
            vv[u] = (float)va.e[u]; vv[8 + u] = (float)vb.e[u];
        }
#pragma unroll
        for (int u = 0; u < 16; u++) spiral2(qq[u], kk[u], vv[u]);
        const int lbase = ri * LDR + (q4 << 4);
        f16x8_u ko0, ko1, vo0, vo1;
#pragma unroll
        for (int u = 0; u < 8; u++) {
            ko0.e[u] = (_Float16)kk[u]; ko1.e[u] = (_Float16)kk[8 + u];
            vo0.e[u] = (_Float16)vv[u]; vo1.e[u] = (_Float16)vv[8 + u];
        }
        *(f16x8*)&k_lds[lbase]     = ko0.v;
        *(f16x8*)&k_lds[lbase + 8] = ko1.v;
        *(f16x8*)&v_lds[lbase]     = vo0.v;
        *(f16x8*)&v_lds[lbase + 8] = vo1.v;
        if (ri >= 16) {
            const int qbase = (ri - 16) * LDR + (q4 << 4);
            f16x8_u qo0, qo1;
#pragma unroll
            for (int u = 0; u < 8; u++) {
                qo0.e[u] = (_Float16)(qq[u] * 0.125f);
                qo1.e[u] = (_Float16)(qq[8 + u] * 0.125f);
            }
            *(f16x8*)&q_lds[qbase]     = qo0.v;
            *(f16x8*)&q_lds[qbase + 8] = qo1.v;
        }
    }
    __syncthreads();

    f16x8_u qv[8];
#pragma unroll
    for (int u = 0; u < 8; u++) qv[u].v = *(const f16x8*)&q_lds[tid * LDR + u * 8];

    float sc[17];
#pragma unroll
    for (int j = 0; j < 17; j++) {
        const _Float16* kr = &k_lds[(tid + j) * LDR];
        float s = 0.f;
#pragma unroll
        for (int u = 0; u < 8; u++) {
            f16x8_u kx; kx.v = *(const f16x8*)&kr[u * 8];
#pragma unroll
            for (int p = 0; p < 4; p++) s = FDOT2(qv[u].h[p], kx.h[p], s);
        }
        sc[j] = s;
    }

    const int t = t0 + tid;
#pragma unroll
    for (int j = 0; j < 17; j++)
        if (j + t < 16) sc[j] = -INFINITY;
    const float sink = sinks[h];
    float m = sink;
#pragma unroll
    for (int j = 0; j < 17; j++) m = fmaxf(m, sc[j]);
    float e[17];
    float denom = expf(sink - m);
#pragma unroll
    for (int j = 0; j < 17; j++) { e[j] = expf(sc[j] - m); denom += e[j]; }
    const float rden = 1.f / denom;
#pragma unroll
    for (int j = 0; j < 17; j++) e[j] *= rden;

    float yacc[64];
#pragma unroll
    for (int d = 0; d < 64; d++) yacc[d] = 0.f;
#pragma unroll
    for (int j = 0; j < 17; j++) {
        const float a = e[j];
        const _Float16* vr = &v_lds[(tid + j) * LDR];
#pragma unroll
        for (int u = 0; u < 8; u++) {
            f16x8_u vx; vx.v = *(const f16x8*)&vr[u * 8];
#pragma unroll
            for (int z = 0; z < 8; z++) yacc[u * 8 + z] += a * (float)vx.e[z];
        }
    }

#pragma unroll
    for (int u = 0; u < 8; u++) {
        f16x8_u yo;
#pragma unroll
        for (int z = 0; z < 8; z++) yo.e[z] = (_Float16)yacc[u * 8 + z];
        *(f16x8*)&q_lds[tid * LDR + u * 8] = yo.v;
    }
    __syncthreads();
    const int ch = tid & 7, rb = tid >> 3;
#pragma unroll
    for (int pass = 0; pass < 8; ++pass) {
        const int r = pass * 16 + rb;
        *(f16x8*)(yh + (bT + t0 + r) * 1024 + (h << 6) + ch * 8) =
            *(const f16x8*)&q_lds[r * LDR + ch * 8];
    }
}

extern "C" void kernel_launch(void* const* d_in, const int* in_sizes, int n_in,
                              void* d_out, int out_size, void* d_ws, size_t ws_size,
                              hipStream_t stream)
{
    const float* x        = (const float*)d_in[0];
    const float* W_attn   = (const float*)d_in[1];
    const float* W_proj   = (const float*)d_in[2];
    const float* sinks    = (const float*)d_in[3];
    const float* ln_scale = (const float*)d_in[4];
    const float* ln_delta = (const float*)d_in[5];
    const float* ln_bias  = (const float*)d_in[6];
    float* out = (float*)d_out;

    char* ws = (char*)d_ws;
    _Float16* xpack  = (_Float16*)(ws);                          //  8 MiB
    _Float16* WaT    = (_Float16*)(ws + (size_t)( 8u << 20));    //  6 MiB
    _Float16* wppack = (_Float16*)(ws + (size_t)(14u << 20));    //  2 MiB
    _Float16* qkv16  = (_Float16*)(ws + (size_t)(16u << 20));    // 24 MiB
    _Float16* yh     = (_Float16*)(ws + (size_t)(40u << 20));    //  8 MiB

    // 1. fused prep
    prep_kernel<<<4352, 256, 0, stream>>>(x, W_attn, W_proj, xpack, WaT, wppack);
    // 2. qkv = x @ W_attn (f16 out): A streamed from pack, B ring-3 LDS
    gemm1_kernel<<<768, 256, 0, stream>>>(xpack, WaT, qkv16);
    // 3. fused spiral^2 + local attention -> yh
    attn_kernel<<<512, 128, 0, stream>>>(qkv16, sinks, yh);
    // 4. out = ln_delta * tanh(ln_scale * (yh @ W_proj)) + ln_bias
    gemm2_kernel<<<512, 256, 0, stream>>>(yh, wppack, out, ln_scale, ln_delta, ln_bias);
}

// Round 10
// 174.327 us; speedup vs baseline: 1.0221x; 1.0127x over previous
//
#include <hip/hip_runtime.h>
#include <hip/hip_fp16.h>
#include <math.h>

#define T_DIM 2048
#define B_DIM 2
#define C_DIM 1024
#define H_DIM 16
#define M_DIM 4096   // B*T

typedef _Float16 f16x8 __attribute__((ext_vector_type(8)));
typedef _Float16 f16x4 __attribute__((ext_vector_type(4)));
typedef _Float16 f16x2 __attribute__((ext_vector_type(2)));
typedef float    f32x4 __attribute__((ext_vector_type(4)));

union f16x8_u { f16x8 v; f16x2 h[4]; _Float16 e[8]; };

#if defined(__has_builtin)
#  if __has_builtin(__builtin_amdgcn_fdot2)
#    define HAVE_FDOT2 1
#  endif
#endif

static __device__ __forceinline__ float FDOT2(f16x2 a, f16x2 b, float c)
{
#ifdef HAVE_FDOT2
    return __builtin_amdgcn_fdot2(a, b, c, false);
#else
    return c + (float)a[0] * (float)b[0] + (float)a[1] * (float)b[1];
#endif
}

// async global->LDS, 16 bytes per lane (wave-uniform base + lane*16 dest)
#define ASYNC_COPY16(gsrc, ldst) \
  __builtin_amdgcn_global_load_lds( \
    (__attribute__((address_space(1))) unsigned int*)(gsrc), \
    (__attribute__((address_space(3))) unsigned int*)(ldst), 16, 0, 0)

// ---------------- fused prep: x->f16  +  both weight transposes ----------------
// grid: [0,4096) conv x; [4096,7168) transpose W_attn; [7168,8192) transpose W_proj
__global__ __launch_bounds__(256) void prep_kernel(const float* __restrict__ x,
                                                   const float* __restrict__ Wa,
                                                   const float* __restrict__ Wp,
                                                   _Float16* __restrict__ xh,
                                                   _Float16* __restrict__ WaT,
                                                   _Float16* __restrict__ WpT)
{
    __shared__ float tile[32][33];
    const int bid = blockIdx.x;
    const int tid = threadIdx.x;
    if (bid < 4096) {
        const int i = bid * 256 + tid;          // 1048576 float4 groups
        float4 v = ((const float4*)x)[i];
        f16x4 o;
        o[0] = (_Float16)v.x; o[1] = (_Float16)v.y;
        o[2] = (_Float16)v.z; o[3] = (_Float16)v.w;
        ((f16x4*)xh)[i] = o;
        return;
    }
    const float* W; _Float16* WT; int N, b;
    if (bid < 4096 + 3072) { W = Wa; WT = WaT; N = 3072; b = bid - 4096; }
    else                   { W = Wp; WT = WpT; N = 1024; b = bid - 7168; }
    const int K = 1024;
    const int bk = b & 31;
    const int bn = b >> 5;
    const int tx = tid & 31, ty = tid >> 5;
#pragma unroll
    for (int r = ty; r < 32; r += 8)
        tile[r][tx] = W[(long)(bk * 32 + r) * N + bn * 32 + tx];
    __syncthreads();
#pragma unroll
    for (int r = ty; r < 32; r += 8)
        WT[(long)(bn * 32 + r) * K + bk * 32 + tx] = (_Float16)tile[tx][r];
}

// ---------------- f16 MFMA GEMM: C[M,N] = A[M,K] * Bt[N,K]^T ----------------
// BM x 128 tile, BK=32, 4 waves. T3 minimum-2-phase recipe:
//   loop t: STAGE(buf^1, t+1) FIRST -> ds_read(buf) -> MFMA -> ONE vmcnt(0)+barrier.
// Stage loads overlap the full ds_read+MFMA window (no pre-barrier self-drain).
// Race-free: stage targets buf^1 while readers use buf; end barrier (lgkm0+vm0)
// publishes tile t+1 AND frees buf before it is restaged next iteration.
// T2 element swizzle kept: e_phys = e_log ^ (((row&2)<<3)|((row&4)<<1)), both sides.
template<int BM, int EPI, int OUTF16>
__global__ __launch_bounds__(256) void gemm_f16_kernel(
    const _Float16* __restrict__ A, const _Float16* __restrict__ Bt,
    void* __restrict__ Cv, int M, int N, int K,
    const float* __restrict__ ln_scale, const float* __restrict__ ln_delta,
    const float* __restrict__ ln_bias)
{
    constexpr int M_REP   = BM / 32;    // 16-row fragments per wave along M
    constexpr int A_LOADS = BM / 64;    // 16B staging loads per thread for A
    __shared__ __attribute__((aligned(16))) _Float16 As[2][BM * 32];
    __shared__ __attribute__((aligned(16))) _Float16 Bs[2][128 * 32];

    const int tid  = threadIdx.x;
    const int lane = tid & 63;
    const int wave = tid >> 6;
    const int wr = wave >> 1, wc = wave & 1;

    // XCD-aware bijective swizzle (gridDim.x % 8 == 0 for both gemms)
    const int nwg = gridDim.x;
    const int q8  = nwg >> 3;
    const int bid = ((int)blockIdx.x & 7) * q8 + ((int)blockIdx.x >> 3);

    const int ntn = N >> 7;
    const int m0 = (bid / ntn) * BM;
    const int n0 = (bid % ntn) << 7;

    f32x4 acc[M_REP][4] = {};

    // staging geometry + source-side swizzle
    const int ea   = tid * 8;
    const int erow = ea >> 5;
    const int xm   = ((erow & 2) << 3) | ((erow & 4) << 1);
    const int ecs  = (ea & 31) ^ xm;
    const _Float16* aptr[A_LOADS];
    const _Float16* bptr[2];
#pragma unroll
    for (int l = 0; l < A_LOADS; ++l)
        aptr[l] = A + (long)(m0 + erow + l * 64) * K + ecs;
#pragma unroll
    for (int l = 0; l < 2; ++l)
        bptr[l] = Bt + (long)(n0 + erow + l * 64) * K + ecs;

    const int fr = lane & 15;
    const int kb = (lane >> 4) << 3;
    const int xr = ((fr & 2) << 3) | ((fr & 4) << 1);
    const int kbs = kb ^ xr;
    const int NT = K >> 5;

    auto stage = [&](int t, int slot) {
        const int k0 = t << 5;
#pragma unroll
        for (int l = 0; l < A_LOADS; ++l) ASYNC_COPY16(aptr[l] + k0, &As[slot][ea + l * 2048]);
#pragma unroll
        for (int l = 0; l < 2; ++l)       ASYNC_COPY16(bptr[l] + k0, &Bs[slot][ea + l * 2048]);
    };

    // prologue: tile 0 into buffer 0; publish
    stage(0, 0);
    __syncthreads();        // vmcnt(0) + barrier: tile 0 resident

    int cur = 0;
    for (int t = 0; t < NT; ++t) {
        if (t + 1 < NT) stage(t + 1, cur ^ 1);   // issue FIRST: overlaps ds_read+MFMA

        f16x8 af[M_REP], bf[4];
#pragma unroll
        for (int i = 0; i < M_REP; i++)
            af[i] = *(const f16x8*)&As[cur][((wr * (BM / 2) + (i << 4) + fr) << 5) + kbs];
#pragma unroll
        for (int j = 0; j < 4; j++)
            bf[j] = *(const f16x8*)&Bs[cur][(((wc << 6) + (j << 4) + fr) << 5) + kbs];
        __builtin_amdgcn_s_setprio(1);
#pragma unroll
        for (int i = 0; i < M_REP; i++)
#pragma unroll
            for (int j = 0; j < 4; j++)
                acc[i][j] = __builtin_amdgcn_mfma_f32_16x16x32_f16(af[i], bf[j], acc[i][j], 0, 0, 0);
        __builtin_amdgcn_s_setprio(0);

        if (t + 1 < NT) {
            __syncthreads();   // single barrier: publishes tile t+1, frees buf cur
            cur ^= 1;
        }
    }

    // epilogue: C/D mapping col = lane&15, row = (lane>>4)*4 + r
    const int rsub = (lane >> 4) << 2;
    const float lsc = EPI ? ln_scale[0] : 0.f;
#pragma unroll
    for (int j = 0; j < 4; j++) {
        const int col = n0 + (wc << 6) + (j << 4) + fr;
        float ld = 0.f, lb = 0.f;
        if (EPI) { ld = ln_delta[col]; lb = ln_bias[col]; }
#pragma unroll
        for (int i = 0; i < M_REP; i++) {
            const int rbase = m0 + wr * (BM / 2) + (i << 4) + rsub;
#pragma unroll
            for (int r = 0; r < 4; r++) {
                float v = acc[i][j][r];
                if (EPI) v = ld * tanhf(lsc * v) + lb;
                if (OUTF16) ((_Float16*)Cv)[(long)(rbase + r) * N + col] = (_Float16)v;
                else        ((float*)Cv)[(long)(rbase + r) * N + col] = v;
            }
        }
    }
}

// ---------------- spiral: two steps on (q,k); v (3rd comp) by value ----------------
__device__ __forceinline__ void spiral2(float& xi, float& xj, float xl)
{
    const float CS = 0.9950041652780258f;   // cos(0.1)
    const float SN = 0.09983341664682815f;  // sin(0.1)
#pragma unroll
    for (int s = 0; s < 2; s++) {
        float r = sqrtf(xi * xi + xj * xj + xl * xl);
        r = fmaxf(r, 1e-8f);
        const float coef = (6.0f - r) / r;
        const float yi = CS * xi - SN * xj;
        const float yj = SN * xi + CS * xj;
        const float nxi = xi + 0.1f * (yi - xi + coef * xi);
        const float nxj = xj + 0.1f * (yj - xj + coef * xj);
        const float nxl = xl + 0.1f * (coef * xl);
        xi = nxi; xj = nxj; xl = nxl;
    }
}

// ---------------- local causal windowed attention, fused spiral, lane-per-row ----------------
#define TB   128
#define ROWS 144
#define LDR  72

__global__ __launch_bounds__(128) void attn_kernel(const _Float16* __restrict__ qkv,
                                                   const float* __restrict__ sinks,
                                                   _Float16* __restrict__ yh)
{
    __shared__ __attribute__((aligned(16))) _Float16 k_lds[ROWS * LDR];
    __shared__ __attribute__((aligned(16))) _Float16 v_lds[ROWS * LDR];
    __shared__ __attribute__((aligned(16))) _Float16 q_lds[TB * LDR];

    const int tid = threadIdx.x;
    const int chunk = blockIdx.x & 15;
    const int h = (blockIdx.x >> 4) & 15;
    const int b = blockIdx.x >> 8;
    const int t0 = chunk * TB;
    const long bT = (long)b * T_DIM;

    for (int s = tid; s < ROWS * 4; s += 128) {
        const int ri = s >> 2, q4 = s & 3;
        const int gr = min(max(t0 - 16 + ri, 0), T_DIM - 1);
        const _Float16* base = qkv + (bT + gr) * 3072 + (h << 6) + (q4 << 4);
        f16x8_u qa, qb, ka, kb2, va, vb;
        qa.v  = *(const f16x8*)(base);        qb.v  = *(const f16x8*)(base + 8);
        ka.v  = *(const f16x8*)(base + 1024); kb2.v = *(const f16x8*)(base + 1032);
        va.v  = *(const f16x8*)(base + 2048); vb.v  = *(const f16x8*)(base + 2056);
        float qq[16], kk[16], vv[16];
#pragma unroll
        for (int u = 0; u < 8; u++) {
            qq[u] = (float)qa.e[u]; qq[8 + u] = (float)qb.e[u];
            kk[u] = (float)ka.e[u]; kk[8 + u] = (float)kb2.e[u];
            vv[u] = (float)va.e[u]; vv[8 + u] = (float)vb.e[u];
        }
#pragma unroll
        for (int u = 0; u < 16; u++) spiral2(qq[u], kk[u], vv[u]);
        const int lbase = ri * LDR + (q4 << 4);
        f16x8_u ko0, ko1, vo0, vo1;
#pragma unroll
        for (int u = 0; u < 8; u++) {
            ko0.e[u] = (_Float16)kk[u]; ko1.e[u] = (_Float16)kk[8 + u];
            vo0.e[u] = (_Float16)vv[u]; vo1.e[u] = (_Float16)vv[8 + u];
        }
        *(f16x8*)&k_lds[lbase]     = ko0.v;
        *(f16x8*)&k_lds[lbase + 8] = ko1.v;
        *(f16x8*)&v_lds[lbase]     = vo0.v;
        *(f16x8*)&v_lds[lbase + 8] = vo1.v;
        if (ri >= 16) {
            const int qbase = (ri - 16) * LDR + (q4 << 4);
            f16x8_u qo0, qo1;
#pragma unroll
            for (int u = 0; u < 8; u++) {
                qo0.e[u] = (_Float16)(qq[u] * 0.125f);
                qo1.e[u] = (_Float16)(qq[8 + u] * 0.125f);
            }
            *(f16x8*)&q_lds[qbase]     = qo0.v;
            *(f16x8*)&q_lds[qbase + 8] = qo1.v;
        }
    }
    __syncthreads();

    f16x8_u qv[8];
#pragma unroll
    for (int u = 0; u < 8; u++) qv[u].v = *(const f16x8*)&q_lds[tid * LDR + u * 8];

    float sc[17];
#pragma unroll
    for (int j = 0; j < 17; j++) {
        const _Float16* kr = &k_lds[(tid + j) * LDR];
        float s = 0.f;
#pragma unroll
        for (int u = 0; u < 8; u++) {
            f16x8_u kx; kx.v = *(const f16x8*)&kr[u * 8];
#pragma unroll
            for (int p = 0; p < 4; p++) s = FDOT2(qv[u].h[p], kx.h[p], s);
        }
        sc[j] = s;
    }

    const int t = t0 + tid;
#pragma unroll
    for (int j = 0; j < 17; j++)
        if (j + t < 16) sc[j] = -INFINITY;
    const float sink = sinks[h];
    float m = sink;
#pragma unroll
    for (int j = 0; j < 17; j++) m = fmaxf(m, sc[j]);
    float e[17];
    float denom = expf(sink - m);
#pragma unroll
    for (int j = 0; j < 17; j++) { e[j] = expf(sc[j] - m); denom += e[j]; }
    const float rden = 1.f / denom;
#pragma unroll
    for (int j = 0; j < 17; j++) e[j] *= rden;

    float yacc[64];
#pragma unroll
    for (int d = 0; d < 64; d++) yacc[d] = 0.f;
#pragma unroll
    for (int j = 0; j < 17; j++) {
        const float a = e[j];
        const _Float16* vr = &v_lds[(tid + j) * LDR];
#pragma unroll
        for (int u = 0; u < 8; u++) {
            f16x8_u vx; vx.v = *(const f16x8*)&vr[u * 8];
#pragma unroll
            for (int z = 0; z < 8; z++) yacc[u * 8 + z] += a * (float)vx.e[z];
        }
    }

#pragma unroll
    for (int u = 0; u < 8; u++) {
        f16x8_u yo;
#pragma unroll
        for (int z = 0; z < 8; z++) yo.e[z] = (_Float16)yacc[u * 8 + z];
        *(f16x8*)&q_lds[tid * LDR + u * 8] = yo.v;
    }
    __syncthreads();
    const int ch = tid & 7, rb = tid >> 3;
#pragma unroll
    for (int pass = 0; pass < 8; ++pass) {
        const int r = pass * 16 + rb;
        *(f16x8*)(yh + (bT + t0 + r) * 1024 + (h << 6) + ch * 8) =
            *(const f16x8*)&q_lds[r * LDR + ch * 8];
    }
}

extern "C" void kernel_launch(void* const* d_in, const int* in_sizes, int n_in,
                              void* d_out, int out_size, void* d_ws, size_t ws_size,
                              hipStream_t stream)
{
    const float* x        = (const float*)d_in[0];
    const float* W_attn   = (const float*)d_in[1];
    const float* W_proj   = (const float*)d_in[2];
    const float* sinks    = (const float*)d_in[3];
    const float* ln_scale = (const float*)d_in[4];
    const float* ln_delta = (const float*)d_in[5];
    const float* ln_bias  = (const float*)d_in[6];
    float* out = (float*)d_out;

    char* ws = (char*)d_ws;
    _Float16* xh    = (_Float16*)(ws);                          //  8 MiB
    _Float16* WaT   = (_Float16*)(ws + (size_t)( 8u << 20));    //  6 MiB
    _Float16* WpT   = (_Float16*)(ws + (size_t)(14u << 20));    //  2 MiB
    _Float16* qkv16 = (_Float16*)(ws + (size_t)(16u << 20));    // 24 MiB
    _Float16* yh    = (_Float16*)(ws + (size_t)(40u << 20));    //  8 MiB

    // 1. fused prep: x->f16 + transpose/convert both weight matrices
    prep_kernel<<<8192, 256, 0, stream>>>(x, W_attn, W_proj, xh, WaT, WpT);
    // 2. qkv = x @ W_attn (f16 out)  M=4096, N=3072, K=1024   (768 blocks, 3/CU)
    gemm_f16_kernel<128, 0, 1><<<32 * 24, 256, 0, stream>>>(xh, WaT, qkv16, 4096, 3072, 1024,
                                                            nullptr, nullptr, nullptr);
    // 3. fused spiral^2 + local attention -> yh
    attn_kernel<<<512, 128, 0, stream>>>(qkv16, sinks, yh);
    // 4. out = ln_delta * tanh(ln_scale * (yh @ W_proj)) + ln_bias  (512 blocks)
    gemm_f16_kernel<64, 1, 0><<<64 * 8, 256, 0, stream>>>(yh, WpT, out, 4096, 1024, 1024,
                                                          ln_scale, ln_delta, ln_bias);
}